// Round 5
// baseline (2306.782 us; speedup 1.0000x reference)
//
#include <hip/hip_runtime.h>
#include <math.h>

// LPKT: one WG (512 thr, 8 waves) per batch element, 99-step recurrence in-kernel.
// h state (129x128 fp32) in REGISTERS, MFMA C-layout, split across half-workgroups
// (half 0 = cb{0,1,2}, half 1 = cb{3,4}); wave's MFMA d-block = 32*(w&3).
// Gate matmul h@W4h on matrix cores at step top (acc 48 VGPR, consumed in update).
// R5: GEMV weights are BF16 (k-quad uint2 repack in d_ws) -> halves the ~900KB/step/WG
// L2 weight stream that stalled R4, and halves VGPRs per outstanding load; unroll
// deepened (B: 16 uint2 in flight, A/C/E fully unrolled). Features stay fp32 in LDS,
// broadcast via v_readlane; h recurrence stays fp32 in registers.

#define BB   64
#define SS   100
#define NQ1  129
#define DK   128
#define NTH  512

// ws dword map: [0,114688) bf16 weight quads, [114688,122880) W4h A-fragments
#define DW_W1A   0
#define DW_W1B   8192
#define DW_W2    16384
#define DW_W3    49152
#define DW_W4L   81920
#define DW_W4I   90112
#define DW_W5A   98304
#define DW_W5B   106496
#define DW_AFRAG 114688
#define DW_TOTAL 122880

typedef __attribute__((ext_vector_type(16))) float floatx16;
typedef __attribute__((ext_vector_type(8)))  short short8v;

__device__ __forceinline__ float frcp(float x) { return __builtin_amdgcn_rcpf(x); }
__device__ __forceinline__ float fsig(float x) { float t = __expf(-x); return frcp(1.0f + t); }
__device__ __forceinline__ float ftanh(float x) {
    x = fminf(20.0f, fmaxf(-20.0f, x));
    float t = __expf(-2.0f * x);
    return (1.0f - t) * frcp(1.0f + t);
}
__device__ __forceinline__ float rlf(float v, int s) {
    return __int_as_float(__builtin_amdgcn_readlane(__float_as_int(v), s));
}
__device__ __forceinline__ unsigned bfbits(float x) {   // fp32 -> bf16 RNE
    unsigned u = __float_as_uint(x);
    return (u + 0x7fffu + ((u >> 16) & 1u)) >> 16;
}
__device__ __forceinline__ float blo(unsigned u) { return __uint_as_float(u << 16); }
__device__ __forceinline__ float bhi(unsigned u) { return __uint_as_float(u & 0xffff0000u); }

// ---- prep: bf16 k-quad weight repack + W4h A-fragment pack -------------------
// weight dword at base + quad*256 + d*2 + half holds bf16 pair {k, k+1},
// k = koff + quad*4 + half*2. Thread-loads of uint2 give one k-quad per column d.
__global__ void prep_kernel(const float* __restrict__ W1, const float* __restrict__ W2,
                            const float* __restrict__ W3, const float* __restrict__ W4,
                            const float* __restrict__ W5, unsigned* __restrict__ ws) {
    int gidx = blockIdx.x * blockDim.x + threadIdx.x;
    if (gidx < DW_AFRAG) {
        const float* src; int koff, dw;
        if      (gidx < DW_W1B) { src = W1; koff = 0;   dw = gidx; }
        else if (gidx < DW_W2)  { src = W1; koff = 128; dw = gidx - DW_W1B; }
        else if (gidx < DW_W3)  { src = W2; koff = 0;   dw = gidx - DW_W2; }
        else if (gidx < DW_W4L) { src = W3; koff = 0;   dw = gidx - DW_W3; }
        else if (gidx < DW_W4I) { src = W4; koff = 128; dw = gidx - DW_W4L; }
        else if (gidx < DW_W5A) { src = W4; koff = 256; dw = gidx - DW_W4I; }
        else if (gidx < DW_W5B) { src = W5; koff = 0;   dw = gidx - DW_W5A; }
        else                    { src = W5; koff = 128; dw = gidx - DW_W5B; }
        int quad = dw >> 8, rem = dw & 255, d = rem >> 1, half = rem & 1;
        int k = koff + quad * 4 + half * 2;
        unsigned lo = bfbits(src[(size_t)k * 128 + d]);
        unsigned hi = bfbits(src[(size_t)(k + 1) * 128 + d]);
        ws[gidx] = lo | (hi << 16);
    } else if (gidx < DW_TOTAL) {
        // A-fragment pack: dword i -> (g, kb, lane, c); elems j=2c,2c+1: k=16kb+8*(lane>>5)+j
        int i = gidx - DW_AFRAG;
        int gg = i >> 11, kb = (i >> 8) & 7, lane = (i >> 2) & 63, c = i & 3;
        int m = lane & 31, hp = lane >> 5;
        int k0 = 16 * kb + 8 * hp + 2 * c;
        unsigned lo = bfbits(W4[(size_t)k0 * 128 + 32 * gg + m]);
        unsigned hi = bfbits(W4[(size_t)(k0 + 1) * 128 + 32 * gg + m]);
        ws[gidx] = lo | (hi << 16);
    }
}

// ---- main kernel --------------------------------------------------------------
__global__ __launch_bounds__(NTH, 2)
void lpkt_kernel(const int* __restrict__ e_data, const int* __restrict__ a_data,
                 const int* __restrict__ it_data, const int* __restrict__ at_data,
                 const float* __restrict__ qm,  const float* __restrict__ h0,
                 const float* __restrict__ Ee,  const float* __restrict__ Eat,
                 const float* __restrict__ Eit,
                 const float* __restrict__ W1, const float* __restrict__ b1,
                 const float* __restrict__ W2, const float* __restrict__ b2,
                 const float* __restrict__ W3, const float* __restrict__ b3,
                 const float* __restrict__ W4, const float* __restrict__ b4,
                 const float* __restrict__ W5, const float* __restrict__ b5,
                 float* __restrict__ out, const unsigned* __restrict__ ws)
{
    const int b    = blockIdx.x;
    const int tid  = threadIdx.x;
    const int lane = tid & 63;
    const int w    = tid >> 6;
    const int g    = w & 3;          // MFMA d-block: rows 32g..32g+31
    const int hh   = w >> 2;         // half: cb set + GEMV k-half
    const int h5   = lane >> 5;
    const int l31  = lane & 31;
    const int ncb  = hh ? 2 : 3;
    const int cb0  = hh ? 3 : 0;
    const int gd   = ((w & 1) << 6) | lane;   // GEMV output d
    const int gmat = (w >> 1) & 1;            // GEMV matrix select
    const uint2* wsu2 = (const uint2*)ws;

    __shared__ __align__(16) unsigned s_frag[10240];  // 40 KB B-fragments (kb*5+cb)
    __shared__ __align__(16) float s_feat[512];   // [lp | it | lc | h_tilde]
    __shared__ __align__(16) float s_eat[256];    // [e_row | at_row]
    __shared__ __align__(16) float s_enext[128];
    __shared__ float s_LG[128], s_c[128], s_s1[128];
    __shared__ __align__(16) float s_red[512];    // (hh*2+mat)*128 + d
    __shared__ float s_ht2[2][128];
    __shared__ float s_q[2][160];
    __shared__ float s_scal[2];

    float hreg[3][16];    // n = 32*(cb0+i)+l31, d = 32g+(r&3)+8*(r>>2)+4*h5
    short8v afr[8];       // A-fragments for d-block g (constant all steps)

    // ---------------- prologue ----------------
    #pragma unroll
    for (int kb = 0; kb < 8; kb++)
        afr[kb] = *(const short8v*)(((const uint4*)ws) + (DW_AFRAG / 4) + g * 512 + kb * 64 + lane);

    #pragma unroll
    for (int i = 0; i < 3; i++) {
        if (i < ncb) {
            int cb = cb0 + i;
            int n = 32 * cb + l31;
            #pragma unroll
            for (int r = 0; r < 16; r++) {
                int d = 32 * g + (r & 3) + 8 * (r >> 2) + 4 * h5;
                hreg[i][r] = (n <= 128) ? h0[(size_t)n * DK + d] : 0.0f;
            }
            #pragma unroll
            for (int q = 0; q < 4; q++) {
                int kb = 2 * g + (q >> 1);
                int lanep = l31 + ((q & 1) << 5);
                int off = (((kb * 5 + cb) << 10) + lanep * 16 + (h5 << 3)) >> 2;
                unsigned lo = bfbits(hreg[i][4 * q])     | (bfbits(hreg[i][4 * q + 1]) << 16);
                unsigned hi = bfbits(hreg[i][4 * q + 2]) | (bfbits(hreg[i][4 * q + 3]) << 16);
                s_frag[off] = lo; s_frag[off + 1] = hi;
            }
        } else {
            #pragma unroll
            for (int r = 0; r < 16; r++) hreg[i][r] = 0.0f;
        }
    }
    {   // s1 partials: quarter = tid>>7 (reads original fp32 W1)
        int qt = tid >> 7, d = tid & 127;
        float z = 0.0f;
        for (int k = 32 * qt; k < 32 * qt + 32; k++) z += W1[(size_t)(256 + k) * DK + d];
        s_red[tid] = z;
    }
    if (tid < 160) {
        int e0 = e_data[b * SS];
        s_q[0][tid] = (tid < NQ1) ? qm[(size_t)e0 * NQ1 + tid] : 0.0f;
    }
    if (tid == 0) out[b * SS] = 0.0f;
    __syncthreads();
    if (tid < 128) {
        s_s1[tid] = s_red[tid] + s_red[128 + tid] + s_red[256 + tid] + s_red[384 + tid];
        s_feat[tid] = 0.0f;            // learning_pre = 0
    }
    if (w == 7) {
        float v = s_q[0][lane] + s_q[0][64 + lane] + ((lane < 32) ? s_q[0][128 + lane] : 0.0f);
        #pragma unroll
        for (int m = 32; m > 0; m >>= 1) v += __shfl_xor(v, m);
        if (lane == 0) s_scal[0] = v;
    }
    __syncthreads();
    {   // ht0 partials (fully unrolled, predicated)
        float ph[16];
        #pragma unroll
        for (int r = 0; r < 16; r++) ph[r] = 0.0f;
        #pragma unroll
        for (int i = 0; i < 3; i++) {
            const bool act = (i < ncb);
            const int cb = act ? (cb0 + i) : 0;
            float qv = act ? s_q[0][32 * cb + l31] : 0.0f;
            #pragma unroll
            for (int r = 0; r < 16; r++) ph[r] += qv * hreg[i][r];
        }
        #pragma unroll
        for (int r = 0; r < 16; r++) {
            float v = ph[r];
            v += __shfl_xor(v, 1); v += __shfl_xor(v, 2); v += __shfl_xor(v, 4);
            v += __shfl_xor(v, 8); v += __shfl_xor(v, 16);
            if (l31 == 0) s_ht2[hh][32 * g + (r & 3) + 8 * (r >> 2) + 4 * h5] = v;
        }
    }
    __syncthreads();
    if (tid < 128) s_feat[384 + tid] = (s_ht2[0][tid] + s_ht2[1][tid]) * frcp(s_scal[0]);
    __syncthreads();

    // ---------------- recurrence ----------------
    for (int t = 0; t < SS - 1; t++) {
        const float* qcur = s_q[t & 1];
        float*       qnxt = s_q[(t + 1) & 1];
        const int base = b * SS + t;
        const int e_t  = e_data[base];
        const int at_t = at_data[base];
        const int it_t = it_data[base];
        const float afl = (float)a_data[base];
        const int e_nx = e_data[base + 1];

        // --- MFMA at step top: logits from step t-1 fragments (ordered by B2..B7
        //     barriers vs the update-phase rewrite; acc=48 VGPR, lives to update) ---
        floatx16 acc[3];
        #pragma unroll
        for (int i = 0; i < 3; i++) acc[i] = (floatx16)(0.0f);
        #pragma unroll
        for (int i = 0; i < 3; i++) {
            if (i < ncb) {
                const int cb = cb0 + i;
                floatx16 a = (floatx16)(0.0f);
                #pragma unroll
                for (int kb = 0; kb < 8; kb++) {
                    short8v bf = *(const short8v*)((const char*)s_frag + (((kb * 5 + cb) << 10) + lane * 16));
                    a = __builtin_amdgcn_mfma_f32_32x32x16_bf16(afr[kb], bf, a, 0, 0, 0);
                }
                acc[i] = a;
            }
        }

        // --- staging ---
        if (w < 4) {
            const float* src; float* dst;
            if      (w == 0) { src = Ee  + (size_t)e_t  * DK; dst = s_eat; }
            else if (w == 1) { src = Eat + (size_t)at_t * DK; dst = s_eat + 128; }
            else if (w == 2) { src = Eit + (size_t)it_t * DK; dst = s_feat + 128; }
            else             { src = Ee  + (size_t)e_nx * DK; dst = s_enext; }
            ((float2*)dst)[lane] = ((const float2*)src)[lane];
        } else {
            int idx = tid - 256;
            if (idx < 160) qnxt[idx] = (idx < NQ1) ? qm[(size_t)e_nx * NQ1 + idx] : 0.0f;
        }
        __syncthreads();   // B1

        // --- phase A: all_learning partials (+ wave7 q_next sum) ---
        if (w == 7) {
            float v = qnxt[lane] + qnxt[64 + lane] + ((lane < 32) ? qnxt[128 + lane] : 0.0f);
            #pragma unroll
            for (int m = 32; m > 0; m >>= 1) v += __shfl_xor(v, m);
            if (lane == 0) s_scal[0] = v;
        }
        {
            const float4* rowp = (const float4*)(gmat ? (s_eat + 128) : s_eat);
            float4 fv = rowp[16 * hh + (lane & 15)];
            const uint2* Wr = wsu2 + (gmat ? (DW_W1B / 2) : (DW_W1A / 2)) + gd;
            float z0 = 0.f, z1 = 0.f, z2 = 0.f, z3 = 0.f;
            #pragma unroll
            for (int s = 0; s < 16; s++) {
                uint2 wv = Wr[(16 * hh + s) * 128];
                z0 += rlf(fv.x, s) * blo(wv.x);  z1 += rlf(fv.y, s) * bhi(wv.x);
                z2 += rlf(fv.z, s) * blo(wv.y);  z3 += rlf(fv.w, s) * bhi(wv.y);
            }
            s_red[(hh * 2 + gmat) * 128 + gd] = (z0 + z1) + (z2 + z3);
        }
        __syncthreads();   // B2
        if (tid < 128)
            s_feat[256 + tid] = b1[tid] + afl * s_s1[tid]
                              + s_red[tid] + s_red[128 + tid] + s_red[256 + tid] + s_red[384 + tid];
        __syncthreads();   // B3

        // --- phase B: feat(512) . W2 / W3, k split across halves ---
        {
            float4 fv = ((const float4*)s_feat)[64 * hh + lane];
            const uint2* Wr = wsu2 + (gmat ? (DW_W3 / 2) : (DW_W2 / 2)) + gd;
            float z0 = 0.f, z1 = 0.f, z2 = 0.f, z3 = 0.f;
            #pragma unroll 16
            for (int s = 0; s < 64; s++) {
                uint2 wv = Wr[(64 * hh + s) * 128];
                z0 += rlf(fv.x, s) * blo(wv.x);  z1 += rlf(fv.y, s) * bhi(wv.x);
                z2 += rlf(fv.z, s) * blo(wv.y);  z3 += rlf(fv.w, s) * bhi(wv.y);
            }
            s_red[(hh * 2 + gmat) * 128 + gd] = (z0 + z1) + (z2 + z3);
        }
        __syncthreads();   // B4
        if (tid < 128) {
            float w2s = s_red[tid]       + s_red[256 + tid];
            float w3s = s_red[128 + tid] + s_red[384 + tid];
            s_LG[tid] = fsig(w3s + b3[tid]) * (ftanh(w2s + b2[tid]) + 1.0f) * 0.5f;
            s_feat[tid] = s_feat[256 + tid];   // lp <- lc
        }
        __syncthreads();   // B5

        // --- phase C: LG.W4l + it.W4i ---
        {
            const float4* rowp = (const float4*)(gmat ? (s_feat + 128) : s_LG);
            float4 fv = rowp[16 * hh + (lane & 15)];
            const uint2* Wr = wsu2 + (gmat ? (DW_W4I / 2) : (DW_W4L / 2)) + gd;
            float z0 = 0.f, z1 = 0.f, z2 = 0.f, z3 = 0.f;
            #pragma unroll
            for (int s = 0; s < 16; s++) {
                uint2 wv = Wr[(16 * hh + s) * 128];
                z0 += rlf(fv.x, s) * blo(wv.x);  z1 += rlf(fv.y, s) * bhi(wv.x);
                z2 += rlf(fv.z, s) * blo(wv.y);  z3 += rlf(fv.w, s) * bhi(wv.y);
            }
            s_red[(hh * 2 + gmat) * 128 + gd] = (z0 + z1) + (z2 + z3);
        }
        __syncthreads();   // B6
        if (tid < 128)
            s_c[tid] = b4[tid] + s_red[tid] + s_red[128 + tid] + s_red[256 + tid] + s_red[384 + tid];
        __syncthreads();   // B7

        // --- update: h = q*LG + sigmoid(logit+c)*h ; new fragments + h_tilde ---
        {
            float lgv[16], cv[16];
            #pragma unroll
            for (int r = 0; r < 16; r++) {
                int d = 32 * g + (r & 3) + 8 * (r >> 2) + 4 * h5;
                lgv[r] = s_LG[d];  cv[r] = s_c[d];
            }
            float ph[16];
            #pragma unroll
            for (int r = 0; r < 16; r++) ph[r] = 0.0f;
            #pragma unroll
            for (int i = 0; i < 3; i++) {
                const bool act = (i < ncb);
                const int cb = act ? (cb0 + i) : 0;
                const int n = 32 * cb + l31;
                const float qcv = act ? qcur[n] : 0.0f;
                const float qnv = act ? qnxt[n] : 0.0f;
                const bool valid = act && ((cb < 4) || (l31 == 0));
                #pragma unroll
                for (int r = 0; r < 16; r++) {
                    float gg = fsig(acc[i][r] + cv[r]);
                    float hn = qcv * lgv[r] + gg * hreg[i][r];
                    hn = valid ? hn : 0.0f;
                    hreg[i][r] = hn;
                    ph[r] += qnv * hn;
                }
                if (act) {
                    #pragma unroll
                    for (int q = 0; q < 4; q++) {
                        int kb = 2 * g + (q >> 1);
                        int lanep = l31 + ((q & 1) << 5);
                        int off = (((kb * 5 + cb) << 10) + lanep * 16 + (h5 << 3)) >> 2;
                        unsigned lo = bfbits(hreg[i][4 * q])     | (bfbits(hreg[i][4 * q + 1]) << 16);
                        unsigned hi = bfbits(hreg[i][4 * q + 2]) | (bfbits(hreg[i][4 * q + 3]) << 16);
                        s_frag[off] = lo; s_frag[off + 1] = hi;
                    }
                }
            }
            #pragma unroll
            for (int r = 0; r < 16; r++) {
                float v = ph[r];
                v += __shfl_xor(v, 1); v += __shfl_xor(v, 2); v += __shfl_xor(v, 4);
                v += __shfl_xor(v, 8); v += __shfl_xor(v, 16);
                if (l31 == 0) s_ht2[hh][32 * g + (r & 3) + 8 * (r >> 2) + 4 * h5] = v;
            }
        }
        __syncthreads();   // B8
        if (tid < 128)
            s_feat[384 + tid] = (s_ht2[0][tid] + s_ht2[1][tid]) * frcp(s_scal[0]);
        __syncthreads();   // B9

        // --- phase E: [e_next, h_tilde] . W5 ---
        {
            const float4* rowp = (const float4*)(gmat ? (s_feat + 384) : s_enext);
            float4 fv = rowp[16 * hh + (lane & 15)];
            const uint2* Wr = wsu2 + (gmat ? (DW_W5B / 2) : (DW_W5A / 2)) + gd;
            float z0 = 0.f, z1 = 0.f, z2 = 0.f, z3 = 0.f;
            #pragma unroll
            for (int s = 0; s < 16; s++) {
                uint2 wv = Wr[(16 * hh + s) * 128];
                z0 += rlf(fv.x, s) * blo(wv.x);  z1 += rlf(fv.y, s) * bhi(wv.x);
                z2 += rlf(fv.z, s) * blo(wv.y);  z3 += rlf(fv.w, s) * bhi(wv.y);
            }
            s_red[(hh * 2 + gmat) * 128 + gd] = (z0 + z1) + (z2 + z3);
        }
        __syncthreads();   // B10
        if (tid < 64) {
            float v = fsig(s_red[lane]      + s_red[128 + lane] + s_red[256 + lane] + s_red[384 + lane] + b5[lane])
                    + fsig(s_red[64 + lane] + s_red[192 + lane] + s_red[320 + lane] + s_red[448 + lane] + b5[64 + lane]);
            #pragma unroll
            for (int m = 32; m > 0; m >>= 1) v += __shfl_xor(v, m);
            if (lane == 0) out[base + 1] = v * (1.0f / 128.0f);
        }
        // no barrier needed: B1 of next iteration orders staging writes vs. readers
    }
}

extern "C" void kernel_launch(void* const* d_in, const int* in_sizes, int n_in,
                              void* d_out, int out_size, void* d_ws, size_t ws_size,
                              hipStream_t stream) {
    const int*   e_data  = (const int*)d_in[0];
    const int*   a_data  = (const int*)d_in[1];
    const int*   it_data = (const int*)d_in[2];
    const int*   at_data = (const int*)d_in[3];
    const float* qm  = (const float*)d_in[4];
    const float* h0  = (const float*)d_in[5];
    const float* Ee  = (const float*)d_in[6];
    const float* Eat = (const float*)d_in[7];
    const float* Eit = (const float*)d_in[8];
    const float* W1  = (const float*)d_in[9];
    const float* b1  = (const float*)d_in[10];
    const float* W2  = (const float*)d_in[11];
    const float* b2  = (const float*)d_in[12];
    const float* W3  = (const float*)d_in[13];
    const float* b3  = (const float*)d_in[14];
    const float* W4  = (const float*)d_in[15];
    const float* b4  = (const float*)d_in[16];
    const float* W5  = (const float*)d_in[17];
    const float* b5  = (const float*)d_in[18];
    float* out = (float*)d_out;
    unsigned* ws = (unsigned*)d_ws;

    prep_kernel<<<dim3((DW_TOTAL + 255) / 256), dim3(256), 0, stream>>>(W1, W2, W3, W4, W5, ws);
    lpkt_kernel<<<dim3(BB), dim3(NTH), 0, stream>>>(
        e_data, a_data, it_data, at_data, qm, h0, Ee, Eat, Eit,
        W1, b1, W2, b2, W3, b3, W4, b4, W5, b5, out, ws);
}